// Round 1
// baseline (976.744 us; speedup 1.0000x reference)
//
#include <hip/hip_runtime.h>
#include <hip/hip_bf16.h>
#include <math.h>

// ---------------------------------------------------------------------------
// DeepSeek MLA forward. Round 10:
//  - attn: software-pipelined (T3+T4 style). Counted s_waitcnt vmcnt(N) + raw
//    s_barrier; never vmcnt(0) in the QK loop. Per chunk: ds_read -> lgkm(0)
//    -> barrier -> stage ch+2 into just-read buffer -> MFMA(setprio) ->
//    vmcnt(8) -> barrier. Chunk4 stages V-half0 (lands under softmax), chunk5
//    stages next-tile ch0, softmax stages next-tile ch1 -> next QK phase and
//    PV half0 start hot. sVt de-aliased from buf0 (LDS 60.4->76.8 KB, still
//    2 blocks/CU of 160 KB). One vmcnt(0) per k-tile remains (V half1).
//  - Everything else (GEMMs, cvt, transpose, mapping) unchanged from R9.
// ---------------------------------------------------------------------------

#define T_DIM 2048
#define HEADS 16
#define D_MODEL 2048
#define NOPE_D 128
#define ROPE_D 64
#define QKD_D 192
#define VD_D 128
#define QLORA 768
#define KVLORA 512
#define KVFULL_D 576
#define SOFTSCALE -96.0f
#define EPS_RMS 1e-6f

typedef __hip_bfloat16 bf;
typedef __attribute__((ext_vector_type(8))) short bf16x8;
typedef __attribute__((ext_vector_type(4))) float f32x4;

#define GLOAD_LDS16(gptr, lptr)                                               \
    __builtin_amdgcn_global_load_lds(                                         \
        (const __attribute__((address_space(1))) unsigned int*)(gptr),        \
        (__attribute__((address_space(3))) unsigned int*)(lptr), 16, 0, 0)

#define WAITV(N) asm volatile("s_waitcnt vmcnt(" #N ")" ::: "memory")
#define WAITL()  asm volatile("s_waitcnt lgkmcnt(0)" ::: "memory")
#define BARRIER() __builtin_amdgcn_s_barrier()

__device__ __forceinline__ void split2(float v, bf* hi, bf* lo) {
    bf h = __float2bfloat16(v);
    *hi = h;
    *lo = __float2bfloat16(v - __bfloat162float(h));
}

// ---------------------------------------------------------------------------
__global__ __launch_bounds__(256) void cvt_split(
    const float* __restrict__ in, bf* __restrict__ hi, bf* __restrict__ lo, int n)
{
    const int i = (blockIdx.x * 256 + threadIdx.x) * 4;
    if (i >= n) return;
    float4 v = *(const float4*)&in[i];
    float vv[4] = {v.x, v.y, v.z, v.w};
#pragma unroll
    for (int u = 0; u < 4; u++) split2(vv[u], &hi[i + u], &lo[i + u]);
}

__global__ __launch_bounds__(256) void cvt_hi(
    const float* __restrict__ in, bf* __restrict__ hi, int n)
{
    const int i = (blockIdx.x * 256 + threadIdx.x) * 4;
    if (i >= n) return;
    float4 v = *(const float4*)&in[i];
    hi[i + 0] = __float2bfloat16(v.x);
    hi[i + 1] = __float2bfloat16(v.y);
    hi[i + 2] = __float2bfloat16(v.z);
    hi[i + 3] = __float2bfloat16(v.w);
}

// ---------------------------------------------------------------------------
__global__ __launch_bounds__(256) void rmsnorm_cvt(
    const float* __restrict__ in, int ld, int D, const float* __restrict__ w,
    bf* __restrict__ hi, bf* __restrict__ lo)
{
    const int row = blockIdx.x;
    const float* r = in + (size_t)row * ld;
    float ss = 0.0f;
    for (int i = threadIdx.x; i < D; i += 256) { float v = r[i]; ss += v * v; }
#pragma unroll
    for (int o = 32; o > 0; o >>= 1) ss += __shfl_down(ss, o, 64);
    __shared__ float red[4];
    if ((threadIdx.x & 63) == 0) red[threadIdx.x >> 6] = ss;
    __syncthreads();
    ss = red[0] + red[1] + red[2] + red[3];
    const float scale = rsqrtf(ss / (float)D + EPS_RMS);
    for (int i = threadIdx.x; i < D; i += 256) {
        const float v = r[i] * scale * w[i];
        split2(v, &hi[(size_t)row * D + i], &lo[(size_t)row * D + i]);
    }
}

// ---------------------------------------------------------------------------
__global__ __launch_bounds__(256) void rope_k_cvt(
    const float* __restrict__ kvfull, const float* __restrict__ freqs,
    bf* __restrict__ kpeh, bf* __restrict__ kpel)
{
    const int idx = blockIdx.x * 256 + threadIdx.x;   // 65536
    const int i = idx & 31, t = idx >> 5;
    const float f = freqs[t * 32 + i];
    float sn, cs; sincosf(f, &sn, &cs);
    const float x1 = kvfull[(size_t)t * KVFULL_D + KVLORA + 2 * i];
    const float x2 = kvfull[(size_t)t * KVFULL_D + KVLORA + 2 * i + 1];
    split2(x1 * cs - x2 * sn, &kpeh[t * 64 + 2 * i], &kpel[t * 64 + 2 * i]);
    split2(x1 * sn + x2 * cs, &kpeh[t * 64 + 2 * i + 1], &kpel[t * 64 + 2 * i + 1]);
}

// ---------------------------------------------------------------------------
__global__ __launch_bounds__(256) void transpose_v(
    const bf* __restrict__ vh, bf* __restrict__ vT)
{
    __shared__ bf s[32][33];
    const int t0 = blockIdx.x * 32, d0 = blockIdx.y * 32, h = blockIdx.z;
    const int tid = threadIdx.x;
    const int i = tid >> 3, j0 = (tid & 7) * 4;
    const bf* src = vh + ((size_t)(t0 + i) * 16 + h) * 128 + d0 + j0;
#pragma unroll
    for (int u = 0; u < 4; u++) s[i][j0 + u] = src[u];
    __syncthreads();
    const int jj = tid >> 3, i0 = (tid & 7) * 4;
    bf* dst = vT + ((size_t)h * 128 + d0 + jj) * 2048 + t0 + i0;
#pragma unroll
    for (int u = 0; u < 4; u++) dst[u] = s[i0 + u][jj];
}

// ---------------------------------------------------------------------------
// Split-bf16 GEMM (score path), 128x128 tile, 3 MFMAs.
// MODE 1: RoPE on d>=128 + split -> Oh/Ol (q). MODE 2: kn/v split write.
// ---------------------------------------------------------------------------
template <int MODE>
__global__ __launch_bounds__(256) void gemm_split(
    const bf* __restrict__ Ah, const bf* __restrict__ Al,
    const bf* __restrict__ Bh, const bf* __restrict__ Bl,
    const float* __restrict__ freqs,
    float* __restrict__ Cf, bf* __restrict__ Oh, bf* __restrict__ Ol,
    bf* __restrict__ O2, int M, int N, int K)
{
    __shared__ bf sAh[128 * 32], sAl[128 * 32];
    __shared__ bf sBh[128 * 32], sBl[128 * 32];

    const int tid = threadIdx.x;
    const int lane = tid & 63, wave = tid >> 6;
    const int row0 = blockIdx.y * 128, col0 = blockIdx.x * 128;
    const int wm = (wave & 1) * 64, wn = (wave >> 1) * 64;
    const int fr = lane & 15, quad = lane >> 4;

    f32x4 acc[4][4];
#pragma unroll
    for (int i = 0; i < 4; i++)
#pragma unroll
        for (int j = 0; j < 4; j++) acc[i][j] = (f32x4){0.f, 0.f, 0.f, 0.f};

    const int trow = tid >> 2;
    const int tcol = (tid & 3) * 8;
    const size_t ldsoff = (size_t)wave * 1024;

    for (int kt = 0; kt < K; kt += 32) {
        __syncthreads();
        GLOAD_LDS16(Ah + (size_t)(row0 + trow) * K + kt + tcol,      (char*)sAh + ldsoff);
        GLOAD_LDS16(Ah + (size_t)(row0 + 64 + trow) * K + kt + tcol, (char*)sAh + 4096 + ldsoff);
        GLOAD_LDS16(Al + (size_t)(row0 + trow) * K + kt + tcol,      (char*)sAl + ldsoff);
        GLOAD_LDS16(Al + (size_t)(row0 + 64 + trow) * K + kt + tcol, (char*)sAl + 4096 + ldsoff);
        GLOAD_LDS16(Bh + (size_t)(col0 + trow) * K + kt + tcol,      (char*)sBh + ldsoff);
        GLOAD_LDS16(Bh + (size_t)(col0 + 64 + trow) * K + kt + tcol, (char*)sBh + 4096 + ldsoff);
        GLOAD_LDS16(Bl + (size_t)(col0 + trow) * K + kt + tcol,      (char*)sBl + ldsoff);
        GLOAD_LDS16(Bl + (size_t)(col0 + 64 + trow) * K + kt + tcol, (char*)sBl + 4096 + ldsoff);
        __syncthreads();

        bf16x8 a_h[4], a_l[4], b_h[4], b_l[4];
#pragma unroll
        for (int mt = 0; mt < 4; mt++) {
            const int r = (wm + mt * 16 + fr) * 32 + quad * 8;
            a_h[mt] = *(const bf16x8*)&sAh[r];
            a_l[mt] = *(const bf16x8*)&sAl[r];
        }
#pragma unroll
        for (int nt = 0; nt < 4; nt++) {
            const int r = (wn + nt * 16 + fr) * 32 + quad * 8;
            b_h[nt] = *(const bf16x8*)&sBh[r];
            b_l[nt] = *(const bf16x8*)&sBl[r];
        }
#pragma unroll
        for (int mt = 0; mt < 4; mt++)
#pragma unroll
            for (int nt = 0; nt < 4; nt++) {
                acc[mt][nt] = __builtin_amdgcn_mfma_f32_16x16x32_bf16(
                    a_l[mt], b_h[nt], acc[mt][nt], 0, 0, 0);
                acc[mt][nt] = __builtin_amdgcn_mfma_f32_16x16x32_bf16(
                    a_h[mt], b_l[nt], acc[mt][nt], 0, 0, 0);
                acc[mt][nt] = __builtin_amdgcn_mfma_f32_16x16x32_bf16(
                    a_h[mt], b_h[nt], acc[mt][nt], 0, 0, 0);
            }
    }

#pragma unroll
    for (int mt = 0; mt < 4; mt++)
#pragma unroll
        for (int nt = 0; nt < 4; nt++) {
            const int colb = col0 + wn + nt * 16;
            const int col = colb + fr;
            if (MODE == 1) {
                const int d0 = colb % 192;
                const bool rope = (d0 >= 128);
                const int ii = (d0 + fr - 128) >> 1;
#pragma unroll
                for (int r = 0; r < 4; r++) {
                    const int row = row0 + wm + mt * 16 + quad * 4 + r;
                    float v = acc[mt][nt][r];
                    if (rope) {
                        const float other = __shfl_xor(v, 1);
                        float sn, cs; sincosf(freqs[row * 32 + ii], &sn, &cs);
                        v = (fr & 1) ? (other * sn + v * cs) : (v * cs - other * sn);
                    }
                    bf h8, l8; split2(v, &h8, &l8);
                    Oh[(size_t)row * N + col] = h8;
                    Ol[(size_t)row * N + col] = l8;
                }
            } else {
                const int hh = col >> 8;
                const int d = col & 255;
#pragma unroll
                for (int r = 0; r < 4; r++) {
                    const int row = row0 + wm + mt * 16 + quad * 4 + r;
                    const float v = acc[mt][nt][r];
                    if (d < 128) {
                        bf h8, l8; split2(v, &h8, &l8);
                        Oh[(size_t)row * 2048 + hh * 128 + d] = h8;
                        Ol[(size_t)row * 2048 + hh * 128 + d] = l8;
                    } else {
                        O2[(size_t)row * 2048 + hh * 128 + (d - 128)] = __float2bfloat16(v);
                    }
                }
            }
        }
}

// ---------------------------------------------------------------------------
// Split-bf16 GEMM, 64x64 tile (small-N shapes: qa N=768, kvfull N=576).
// ---------------------------------------------------------------------------
__global__ __launch_bounds__(256) void gemm_split64(
    const bf* __restrict__ Ah, const bf* __restrict__ Al,
    const bf* __restrict__ Bh, const bf* __restrict__ Bl,
    float* __restrict__ Cf, int M, int N, int K)
{
    __shared__ bf sAh[64 * 32], sAl[64 * 32];
    __shared__ bf sBh[64 * 32], sBl[64 * 32];

    const int tid = threadIdx.x;
    const int lane = tid & 63, wave = tid >> 6;
    const int row0 = blockIdx.y * 64, col0 = blockIdx.x * 64;
    const int wm = (wave & 1) * 32, wn = (wave >> 1) * 32;
    const int fr = lane & 15, quad = lane >> 4;

    f32x4 acc[2][2];
#pragma unroll
    for (int i = 0; i < 2; i++)
#pragma unroll
        for (int j = 0; j < 2; j++) acc[i][j] = (f32x4){0.f, 0.f, 0.f, 0.f};

    const int trow = tid >> 2;
    const int tcol = (tid & 3) * 8;
    const size_t ldsoff = (size_t)wave * 1024;

    for (int kt = 0; kt < K; kt += 32) {
        __syncthreads();
        GLOAD_LDS16(Ah + (size_t)(row0 + trow) * K + kt + tcol, (char*)sAh + ldsoff);
        GLOAD_LDS16(Al + (size_t)(row0 + trow) * K + kt + tcol, (char*)sAl + ldsoff);
        GLOAD_LDS16(Bh + (size_t)(col0 + trow) * K + kt + tcol, (char*)sBh + ldsoff);
        GLOAD_LDS16(Bl + (size_t)(col0 + trow) * K + kt + tcol, (char*)sBl + ldsoff);
        __syncthreads();

        bf16x8 a_h[2], a_l[2], b_h[2], b_l[2];
#pragma unroll
        for (int mt = 0; mt < 2; mt++) {
            const int r = (wm + mt * 16 + fr) * 32 + quad * 8;
            a_h[mt] = *(const bf16x8*)&sAh[r];
            a_l[mt] = *(const bf16x8*)&sAl[r];
        }
#pragma unroll
        for (int nt = 0; nt < 2; nt++) {
            const int r = (wn + nt * 16 + fr) * 32 + quad * 8;
            b_h[nt] = *(const bf16x8*)&sBh[r];
            b_l[nt] = *(const bf16x8*)&sBl[r];
        }
#pragma unroll
        for (int mt = 0; mt < 2; mt++)
#pragma unroll
            for (int nt = 0; nt < 2; nt++) {
                acc[mt][nt] = __builtin_amdgcn_mfma_f32_16x16x32_bf16(
                    a_l[mt], b_h[nt], acc[mt][nt], 0, 0, 0);
                acc[mt][nt] = __builtin_amdgcn_mfma_f32_16x16x32_bf16(
                    a_h[mt], b_l[nt], acc[mt][nt], 0, 0, 0);
                acc[mt][nt] = __builtin_amdgcn_mfma_f32_16x16x32_bf16(
                    a_h[mt], b_h[nt], acc[mt][nt], 0, 0, 0);
            }
    }

#pragma unroll
    for (int mt = 0; mt < 2; mt++)
#pragma unroll
        for (int nt = 0; nt < 2; nt++)
#pragma unroll
            for (int r = 0; r < 4; r++)
                Cf[(size_t)(row0 + wm + mt * 16 + quad * 4 + r) * N +
                   col0 + wn + nt * 16 + fr] = acc[mt][nt][r];
}

// ---------------------------------------------------------------------------
// Plain bf16 GEMM (post-softmax out-projection): C = A @ B^T, single MFMA.
// ---------------------------------------------------------------------------
__global__ __launch_bounds__(256) void gemm_bf16(
    const bf* __restrict__ Ah, const bf* __restrict__ Bh,
    float* __restrict__ Cf, int M, int N, int K)
{
    __shared__ bf sAh[128 * 32];
    __shared__ bf sBh[128 * 32];

    const int tid = threadIdx.x;
    const int lane = tid & 63, wave = tid >> 6;
    const int row0 = blockIdx.y * 128, col0 = blockIdx.x * 128;
    const int wm = (wave & 1) * 64, wn = (wave >> 1) * 64;
    const int fr = lane & 15, quad = lane >> 4;

    f32x4 acc[4][4];
#pragma unroll
    for (int i = 0; i < 4; i++)
#pragma unroll
        for (int j = 0; j < 4; j++) acc[i][j] = (f32x4){0.f, 0.f, 0.f, 0.f};

    const int trow = tid >> 2;
    const int tcol = (tid & 3) * 8;
    const size_t ldsoff = (size_t)wave * 1024;

    for (int kt = 0; kt < K; kt += 32) {
        __syncthreads();
        GLOAD_LDS16(Ah + (size_t)(row0 + trow) * K + kt + tcol,      (char*)sAh + ldsoff);
        GLOAD_LDS16(Ah + (size_t)(row0 + 64 + trow) * K + kt + tcol, (char*)sAh + 4096 + ldsoff);
        GLOAD_LDS16(Bh + (size_t)(col0 + trow) * K + kt + tcol,      (char*)sBh + ldsoff);
        GLOAD_LDS16(Bh + (size_t)(col0 + 64 + trow) * K + kt + tcol, (char*)sBh + 4096 + ldsoff);
        __syncthreads();

        bf16x8 a_h[4], b_h[4];
#pragma unroll
        for (int mt = 0; mt < 4; mt++)
            a_h[mt] = *(const bf16x8*)&sAh[(wm + mt * 16 + fr) * 32 + quad * 8];
#pragma unroll
        for (int nt = 0; nt < 4; nt++)
            b_h[nt] = *(const bf16x8*)&sBh[(wn + nt * 16 + fr) * 32 + quad * 8];
#pragma unroll
        for (int mt = 0; mt < 4; mt++)
#pragma unroll
            for (int nt = 0; nt < 4; nt++)
                acc[mt][nt] = __builtin_amdgcn_mfma_f32_16x16x32_bf16(
                    a_h[mt], b_h[nt], acc[mt][nt], 0, 0, 0);
    }

#pragma unroll
    for (int mt = 0; mt < 4; mt++)
#pragma unroll
        for (int nt = 0; nt < 4; nt++)
#pragma unroll
            for (int r = 0; r < 4; r++)
                Cf[(size_t)(row0 + wm + mt * 16 + quad * 4 + r) * N +
                   col0 + wn + nt * 16 + fr] = acc[mt][nt][r];
}

// ---------------------------------------------------------------------------
// Pipelined monolithic MFMA flash attention. 512 blocks = (h, qt),
// heavy/light paired. Counted-vmcnt software pipeline:
//   chunk ch: [ds_read frags | lgkm(0) | barrier | stage ch+2 -> just-read
//              buffer | 24 MFMA (setprio) | vmcnt(8) | barrier]
//   ch4 stages V-half0 (lands under softmax); ch5 stages next-tile ch0;
//   softmax stages next-tile ch1. PV: Ps half0 write -> vmcnt(16) (V0 landed,
//   next ch0/ch1 still in flight) -> reads -> barrier -> stage V1 + Ps half1
//   write overlapped with half0 MFMAs -> vmcnt(0) -> half1.
// LDS: buf0@0 buf1@24576 (each Qh/Ql/Kh/Kl 4/4/8/8K), sVt@49152 (16K),
// Ps@65536 ([64][72] bf16), redM@74752, redS@75776 -> 76800 B, 2 blocks/CU.
// ---------------------------------------------------------------------------
#define STAGE_QK(buf_, k0_, d0_)                                              \
  do {                                                                        \
    GLOAD_LDS16(qh + ((size_t)(q0 + trow) * 16 + h) * 192 + (d0_) + tcol, (buf_) + loff);          \
    GLOAD_LDS16(ql + ((size_t)(q0 + trow) * 16 + h) * 192 + (d0_) + tcol, (buf_) + 4096 + loff);   \
    if ((d0_) < 128) {                                                        \
      GLOAD_LDS16(knh + ((size_t)((k0_) + trow) * 16 + h) * 128 + (d0_) + tcol,      (buf_) + 8192 + loff);  \
      GLOAD_LDS16(knh + ((size_t)((k0_) + 64 + trow) * 16 + h) * 128 + (d0_) + tcol, (buf_) + 12288 + loff); \
      GLOAD_LDS16(knl + ((size_t)((k0_) + trow) * 16 + h) * 128 + (d0_) + tcol,      (buf_) + 16384 + loff); \
      GLOAD_LDS16(knl + ((size_t)((k0_) + 64 + trow) * 16 + h) * 128 + (d0_) + tcol, (buf_) + 20480 + loff); \
    } else {                                                                  \
      GLOAD_LDS16(kpeh + (size_t)((k0_) + trow) * 64 + (d0_) - 128 + tcol,      (buf_) + 8192 + loff);  \
      GLOAD_LDS16(kpeh + (size_t)((k0_) + 64 + trow) * 64 + (d0_) - 128 + tcol, (buf_) + 12288 + loff); \
      GLOAD_LDS16(kpel + (size_t)((k0_) + trow) * 64 + (d0_) - 128 + tcol,      (buf_) + 16384 + loff); \
      GLOAD_LDS16(kpel + (size_t)((k0_) + 64 + trow) * 64 + (d0_) - 128 + tcol, (buf_) + 20480 + loff); \
    }                                                                         \
  } while (0)

#define STAGE_V(kb_)                                                          \
  do {                                                                        \
    GLOAD_LDS16(vT + ((size_t)(h * 128 + trow)) * 2048 + (kb_) + tcol,           sVb + loff);          \
    GLOAD_LDS16(vT + ((size_t)(h * 128 + 64 + trow)) * 2048 + (kb_) + tcol,      sVb + 4096 + loff);   \
    GLOAD_LDS16(vT + ((size_t)(h * 128 + trow)) * 2048 + (kb_) + 32 + tcol,      sVb + 8192 + loff);   \
    GLOAD_LDS16(vT + ((size_t)(h * 128 + 64 + trow)) * 2048 + (kb_) + 32 + tcol, sVb + 12288 + loff);  \
  } while (0)

__global__ __launch_bounds__(256, 2) void attn_mfma(
    const bf* __restrict__ qh, const bf* __restrict__ ql,
    const bf* __restrict__ knh, const bf* __restrict__ knl,
    const bf* __restrict__ kpeh, const bf* __restrict__ kpel,
    const bf* __restrict__ vT, bf* __restrict__ yh)
{
    const int bid = blockIdx.x;
    const int h = bid & 15;
    const int qt = (bid < 256) ? (31 - (bid >> 4)) : ((bid - 256) >> 4);

    const int tid = threadIdx.x;
    const int lane = tid & 63, wave = tid >> 6;
    const int fr = lane & 15, quad = lane >> 4;
    const int wn = wave * 32;

    __shared__ __align__(16) char smem[76800];
    bf* Ps      = (bf*)(smem + 65536);     // [64][72]
    float* redM = (float*)(smem + 74752);  // [64][4]
    float* redS = (float*)(smem + 75776);  // [64][4]
    char* sVb   = smem + 49152;            // 16 KB V half
    bf* sVt     = (bf*)sVb;

    float m_i[16], l_i[16], al[16];
    f32x4 O[4][2];
#pragma unroll
    for (int i = 0; i < 16; i++) { m_i[i] = -INFINITY; l_i[i] = 0.0f; }
#pragma unroll
    for (int mt = 0; mt < 4; mt++)
#pragma unroll
        for (int nt = 0; nt < 2; nt++) O[mt][nt] = (f32x4){0.f, 0.f, 0.f, 0.f};

    const int q0 = qt * 64;
    const int nkt = ((qt + 1) * 64 + 127) >> 7;
    const int trow = tid >> 2, tcol = (tid & 3) * 8;
    const size_t loff = (size_t)wave * 1024;

    // prologue: stage k-tile 0 chunks 0,1 into buf0,buf1
    STAGE_QK(smem, 0, 0);
    STAGE_QK(smem + 24576, 0, 32);
    WAITV(8);            // chunk 0 landed (chunk 1 still in flight)
    BARRIER();

    for (int kt = 0; kt < nkt; kt++) {
        const int k0 = kt * 128;
        const bool more = (kt + 1 < nkt);
        f32x4 S[4][2];
#pragma unroll
        for (int mt = 0; mt < 4; mt++)
#pragma unroll
            for (int nt = 0; nt < 2; nt++) S[mt][nt] = (f32x4){0.f, 0.f, 0.f, 0.f};

        // ---- S = Q.K^T over 192 dims: 6 pipelined chunks ----
#pragma unroll
        for (int ch = 0; ch < 6; ch++) {
            char* buf = smem + ((ch & 1) ? 24576 : 0);
            const bf* sQh = (const bf*)buf;
            const bf* sQl = (const bf*)(buf + 4096);
            const bf* sKh = (const bf*)(buf + 8192);
            const bf* sKl = (const bf*)(buf + 16384);
            bf16x8 a_h[4], a_l[4], b_h[2], b_l[2];
#pragma unroll
            for (int mt = 0; mt < 4; mt++) {
                const int r = (mt * 16 + fr) * 32 + quad * 8;
                a_h[mt] = *(const bf16x8*)&sQh[r];
                a_l[mt] = *(const bf16x8*)&sQl[r];
            }
#pragma unroll
            for (int nt = 0; nt < 2; nt++) {
                const int r = (wn + nt * 16 + fr) * 32 + quad * 8;
                b_h[nt] = *(const bf16x8*)&sKh[r];
                b_l[nt] = *(const bf16x8*)&sKl[r];
            }
            WAITL();           // own frag reads in regs
            BARRIER();         // block-wide: buf fully read -> overwritable
            if (ch < 4) {
                STAGE_QK(buf, k0, (ch + 2) * 32);
            } else if (ch == 4) {
                STAGE_V(k0);                       // V half0, lands under softmax
            } else if (more) {
                STAGE_QK(smem, k0 + 128, 0);       // next-tile ch0 -> buf0
            }
            __builtin_amdgcn_s_setprio(1);
#pragma unroll
            for (int mt = 0; mt < 4; mt++)
#pragma unroll
                for (int nt = 0; nt < 2; nt++) {
                    S[mt][nt] = __builtin_amdgcn_mfma_f32_16x16x32_bf16(
                        a_l[mt], b_h[nt], S[mt][nt], 0, 0, 0);
                    S[mt][nt] = __builtin_amdgcn_mfma_f32_16x16x32_bf16(
                        a_h[mt], b_l[nt], S[mt][nt], 0, 0, 0);
                    S[mt][nt] = __builtin_amdgcn_mfma_f32_16x16x32_bf16(
                        a_h[mt], b_h[nt], S[mt][nt], 0, 0, 0);
                }
            __builtin_amdgcn_s_setprio(0);
            if (ch < 4)       { WAITV(8); BARRIER(); }   // chunk ch+1 landed
            else if (ch == 4) { WAITV(4); BARRIER(); }   // chunk 5 landed, V0 in flight
            // ch==5: fall through to softmax (no vm-dependent reads yet)
        }

        // ---- online softmax (fp32, block-wide row reductions) ----
#pragma unroll
        for (int mt = 0; mt < 4; mt++)
#pragma unroll
            for (int rr = 0; rr < 4; rr++) {
                const int ri = mt * 16 + quad * 4 + rr;
                const int rowg = q0 + ri;
                float v0 = S[mt][0][rr] * SOFTSCALE;
                float v1 = S[mt][1][rr] * SOFTSCALE;
                if (k0 + wn + fr > rowg)      v0 = -INFINITY;
                if (k0 + wn + 16 + fr > rowg) v1 = -INFINITY;
                S[mt][0][rr] = v0; S[mt][1][rr] = v1;
                float pm = fmaxf(v0, v1);
#pragma unroll
                for (int o = 1; o < 16; o <<= 1) pm = fmaxf(pm, __shfl_xor(pm, o, 64));
                if (fr == 0) redM[ri * 4 + wave] = pm;
            }
        if (more) STAGE_QK(smem + 24576, k0 + 128, 32);  // next-tile ch1 -> buf1
        WAITL();          // redM writes committed (vm prefetches stay in flight)
        BARRIER();
#pragma unroll
        for (int mt = 0; mt < 4; mt++)
#pragma unroll
            for (int rr = 0; rr < 4; rr++) {
                const int idx = mt * 4 + rr;
                const int ri = mt * 16 + quad * 4 + rr;
                const float4 g = *(const float4*)&redM[ri * 4];
                const float gm = fmaxf(fmaxf(g.x, g.y), fmaxf(g.z, g.w));
                const float mn = fmaxf(m_i[idx], gm);
                al[idx] = __expf(m_i[idx] - mn);
                m_i[idx] = mn;
                const float p0 = __expf(S[mt][0][rr] - mn);
                const float p1 = __expf(S[mt][1][rr] - mn);
                S[mt][0][rr] = p0; S[mt][1][rr] = p1;   // keep p for PV store
                float ps = p0 + p1;
#pragma unroll
                for (int o = 1; o < 16; o <<= 1) ps += __shfl_xor(ps, o, 64);
                if (fr == 0) redS[ri * 4 + wave] = ps;
            }
#pragma unroll
        for (int mt = 0; mt < 4; mt++)
#pragma unroll
            for (int nt = 0; nt < 2; nt++)
#pragma unroll
                for (int rr = 0; rr < 4; rr++) O[mt][nt][rr] *= al[mt * 4 + rr];
        WAITL();
        BARRIER();
#pragma unroll
        for (int mt = 0; mt < 4; mt++)
#pragma unroll
            for (int rr = 0; rr < 4; rr++) {
                const int idx = mt * 4 + rr;
                const int ri = mt * 16 + quad * 4 + rr;
                const float4 s4 = *(const float4*)&redS[ri * 4];
                l_i[idx] = l_i[idx] * al[idx] + (s4.x + s4.y + s4.z + s4.w);
            }

        // ---- PV: half0 (keys k0..k0+63) ----
        if ((wave >> 1) == 0) {
#pragma unroll
            for (int mt = 0; mt < 4; mt++)
#pragma unroll
                for (int rr = 0; rr < 4; rr++) {
                    const int ri = mt * 16 + quad * 4 + rr;
                    Ps[ri * 72 + wn + fr]      = __float2bfloat16(S[mt][0][rr]);
                    Ps[ri * 72 + wn + 16 + fr] = __float2bfloat16(S[mt][1][rr]);
                }
        }
        WAITL();                       // Ps half0 writes committed
        if (more) { WAITV(16); }       // V0 (oldest 4) landed; nch0+nch1 in flight
        else      { WAITV(0);  }       // only V0 outstanding
        BARRIER();

        bf16x8 ap[2][4], bv[2][2];
#pragma unroll
        for (int vc = 0; vc < 2; vc++) {
#pragma unroll
            for (int mt = 0; mt < 4; mt++)
                ap[vc][mt] = *(const bf16x8*)&Ps[(mt * 16 + fr) * 72 + vc * 32 + quad * 8];
#pragma unroll
            for (int nt = 0; nt < 2; nt++)
                bv[vc][nt] = *(const bf16x8*)&sVt[vc * 4096 + (wn + nt * 16 + fr) * 32 + quad * 8];
        }
        WAITL();
        BARRIER();                     // Ps + sVt fully read -> overwritable
        STAGE_V(k0 + 64);              // V half1 -> sVt
        if ((wave >> 1) == 1) {
            const int kc = wn - 64;
#pragma unroll
            for (int mt = 0; mt < 4; mt++)
#pragma unroll
                for (int rr = 0; rr < 4; rr++) {
                    const int ri = mt * 16 + quad * 4 + rr;
                    Ps[ri * 72 + kc + fr]      = __float2bfloat16(S[mt][0][rr]);
                    Ps[ri * 72 + kc + 16 + fr] = __float2bfloat16(S[mt][1][rr]);
                }
        }
        __builtin_amdgcn_s_setprio(1);
#pragma unroll
        for (int vc = 0; vc < 2; vc++)
#pragma unroll
            for (int mt = 0; mt < 4; mt++)
#pragma unroll
                for (int nt = 0; nt < 2; nt++)
                    O[mt][nt] = __builtin_amdgcn_mfma_f32_16x16x32_bf16(
                        ap[vc][mt], bv[vc][nt], O[mt][nt], 0, 0, 0);
        __builtin_amdgcn_s_setprio(0);

        // ---- PV: half1 (keys k0+64..k0+127) ----
        WAITL();                       // Ps half1 writes committed
        WAITV(0);                      // V1 landed (drains nch0/nch1 too - old)
        BARRIER();
#pragma unroll
        for (int vc = 0; vc < 2; vc++) {
#pragma unroll
            for (int mt = 0; mt < 4; mt++)
                ap[vc][mt] = *(const bf16x8*)&Ps[(mt * 16 + fr) * 72 + vc * 32 + quad * 8];
#pragma unroll
            for (int nt = 0; nt < 2; nt++)
                bv[vc][nt] = *(const bf16x8*)&sVt[vc * 4096 + (wn + nt * 16 + fr) * 32 + quad * 8];
        }
        __builtin_amdgcn_s_setprio(1);
#pragma unroll
        for (int vc = 0; vc < 2; vc++)
#pragma unroll
            for (int mt = 0; mt < 4; mt++)
#pragma unroll
                for (int nt = 0; nt < 2; nt++)
                    O[mt][nt] = __builtin_amdgcn_mfma_f32_16x16x32_bf16(
                        ap[vc][mt], bv[vc][nt], O[mt][nt], 0, 0, 0);
        __builtin_amdgcn_s_setprio(0);
        // next iteration's ch0 read of buf0 is protected by the WAITV(0)+
        // BARRIER above; its first WAITL+BARRIER protects these frag reads.
    }

    // ---- epilogue: y = O / l (bf16) ----
#pragma unroll
    for (int mt = 0; mt < 4; mt++)
#pragma unroll
        for (int rr = 0; rr < 4; rr++) {
            const float inv = 1.0f / l_i[mt * 4 + rr];
            const int row = q0 + mt * 16 + quad * 4 + rr;
#pragma unroll
            for (int nt = 0; nt < 2; nt++)
                yh[((size_t)row * 16 + h) * 128 + wn + nt * 16 + fr] =
                    __float2bfloat16(O[mt][nt][rr] * inv);
        }
}

// ---------------------------------------------------------------------------
// Workspace (peak < 85 MB):
//  A  @0        : xh(8.39) xl(8.39) -> yh@0, vT@8.39
//  AR @16.78    : (16.78) GEMM temporaries -> woh
//  persistent   : qh@33.55 ql@46.14 knh@58.72 knl@67.11 vh@75.50
//                 kpeh@83.89 kpel@84.15
// ---------------------------------------------------------------------------
extern "C" void kernel_launch(void* const* d_in, const int* in_sizes, int n_in,
                              void* d_out, int out_size, void* d_ws, size_t ws_size,
                              hipStream_t stream)
{
    const float* x        = (const float*)d_in[0];
    const float* freqs    = (const float*)d_in[1];
    const float* wq_a     = (const float*)d_in[3];
    const float* q_norm_w = (const float*)d_in[4];
    const float* wq_b     = (const float*)d_in[5];
    const float* wkv_a    = (const float*)d_in[6];
    const float* kv_norm_w= (const float*)d_in[7];
    const float* wkv_b    = (const float*)d_in[8];
    const float* wo       = (const float*)d_in[9];
    float* out            = (float*)d_out;

    char* ws = (char*)d_ws;
    bf* xh = (bf*)(ws);
    bf* xl = (bf*)(ws + 8388608);
    bf* yh = (bf*)(ws);                   // after x dead
    bf* vT = (bf*)(ws + 8388608);         // after x dead
    char* AR = ws + 16777216;
    bf*    wah    = (bf*)(AR);
    bf*    wal    = (bf*)(AR + 3145728);
    float* qa     = (float*)(AR + 6291456);
    bf*    qah    = (bf*)(AR);
    bf*    qal    = (bf*)(AR + 3145728);
    bf*    wbh    = (bf*)(AR + 6291456);
    bf*    wbl    = (bf*)(AR + 11010048);
    bf*    kah    = (bf*)(AR);
    bf*    kal    = (bf*)(AR + 2359296);
    float* kvfull = (float*)(AR + 4718592);
    bf*    ckvh   = (bf*)(AR + 9437184);
    bf*    ckvl   = (bf*)(AR + 11534336);
    bf*    wvh    = (bf*)(AR);
    bf*    wvl    = (bf*)(AR + 4194304);
    bf*    woh    = (bf*)(AR);
    bf* qh   = (bf*)(ws + 33554432);
    bf* ql   = (bf*)(ws + 46137344);
    bf* knh  = (bf*)(ws + 58720256);
    bf* knl  = (bf*)(ws + 67108864);
    bf* vh   = (bf*)(ws + 75497472);
    bf* kpeh = (bf*)(ws + 83886080);
    bf* kpel = (bf*)(ws + 84148224);

    dim3 blk(256);

    cvt_split<<<4096, blk, 0, stream>>>(x, xh, xl, D_MODEL * D_MODEL);
    cvt_split<<<1536, blk, 0, stream>>>(wq_a, wah, wal, QLORA * D_MODEL);
    gemm_split64<<<dim3(12, 32), blk, 0, stream>>>(
        xh, xl, wah, wal, qa, T_DIM, QLORA, D_MODEL);
    rmsnorm_cvt<<<T_DIM, blk, 0, stream>>>(qa, QLORA, QLORA, q_norm_w, qah, qal);
    cvt_split<<<2304, blk, 0, stream>>>(wq_b, wbh, wbl, 3072 * QLORA);
    gemm_split<1><<<dim3(24, 16), blk, 0, stream>>>(
        qah, qal, wbh, wbl, freqs, nullptr, qh, ql, nullptr,
        T_DIM, 3072, QLORA);
    cvt_split<<<1152, blk, 0, stream>>>(wkv_a, kah, kal, KVFULL_D * D_MODEL);
    gemm_split64<<<dim3(9, 32), blk, 0, stream>>>(
        xh, xl, kah, kal, kvfull, T_DIM, KVFULL_D, D_MODEL);
    rope_k_cvt<<<256, blk, 0, stream>>>(kvfull, freqs, kpeh, kpel);
    rmsnorm_cvt<<<T_DIM, blk, 0, stream>>>(kvfull, KVFULL_D, KVLORA, kv_norm_w, ckvh, ckvl);
    cvt_split<<<2048, blk, 0, stream>>>(wkv_b, wvh, wvl, 4096 * KVLORA);
    gemm_split<2><<<dim3(32, 16), blk, 0, stream>>>(
        ckvh, ckvl, wvh, wvl, nullptr, nullptr, knh, knl, vh,
        T_DIM, 4096, KVLORA);
    transpose_v<<<dim3(64, 4, 16), blk, 0, stream>>>(vh, vT);
    attn_mfma<<<dim3(512), blk, 0, stream>>>(
        qh, ql, knh, knl, kpeh, kpel, vT, yh);
    cvt_hi<<<4096, blk, 0, stream>>>(wo, woh, D_MODEL * D_MODEL);
    gemm_bf16<<<dim3(16, 16), blk, 0, stream>>>(
        yh, woh, out, T_DIM, D_MODEL, D_MODEL);
}

// Round 2
// 791.885 us; speedup vs baseline: 1.2334x; 1.2334x over previous
//
#include <hip/hip_runtime.h>
#include <hip/hip_bf16.h>
#include <math.h>

// ---------------------------------------------------------------------------
// DeepSeek MLA forward. Round 11:
//  - R10 post-mortem: counted-vmcnt pipeline web DESYNCED the L2 convoy
//    (FETCH 122->324 MB, 2.2x slower). Reverted.
//  - attn rewrite: register-direct operands. Q/K/V fragments are consumed by
//    exactly one wave -> load global->VGPR (dwordx4) instead of LDS staging.
//    QK phase: zero barriers, compiler-pipelined loads (it emits counted
//    vmcnt itself; only barrier drains were the problem). LDS only for Ps
//    (cross-wave P exchange) + redM/redS -> 2 lgkm-only barriers per k-tile
//    (no vmcnt drain: raw s_barrier + lgkmcnt(0)). V loads issued before the
//    exp phase so latency hides under softmax VALU. Monolithic sequential-k
//    mapping, heavy/light pairing, arithmetic order: unchanged from R9.
//    LDS 19.5 KB (was 60.4). Same grid (512 = 2 blocks/CU).
//  - Everything else (GEMMs, cvt, transpose, mapping) unchanged.
// ---------------------------------------------------------------------------

#define T_DIM 2048
#define HEADS 16
#define D_MODEL 2048
#define NOPE_D 128
#define ROPE_D 64
#define QKD_D 192
#define VD_D 128
#define QLORA 768
#define KVLORA 512
#define KVFULL_D 576
#define SOFTSCALE -96.0f
#define EPS_RMS 1e-6f

typedef __hip_bfloat16 bf;
typedef __attribute__((ext_vector_type(8))) short bf16x8;
typedef __attribute__((ext_vector_type(4))) float f32x4;

#define GLOAD_LDS16(gptr, lptr)                                               \
    __builtin_amdgcn_global_load_lds(                                         \
        (const __attribute__((address_space(1))) unsigned int*)(gptr),        \
        (__attribute__((address_space(3))) unsigned int*)(lptr), 16, 0, 0)

#define WAITL()  asm volatile("s_waitcnt lgkmcnt(0)" ::: "memory")
#define BARRIER() __builtin_amdgcn_s_barrier()

__device__ __forceinline__ void split2(float v, bf* hi, bf* lo) {
    bf h = __float2bfloat16(v);
    *hi = h;
    *lo = __float2bfloat16(v - __bfloat162float(h));
}

// ---------------------------------------------------------------------------
__global__ __launch_bounds__(256) void cvt_split(
    const float* __restrict__ in, bf* __restrict__ hi, bf* __restrict__ lo, int n)
{
    const int i = (blockIdx.x * 256 + threadIdx.x) * 4;
    if (i >= n) return;
    float4 v = *(const float4*)&in[i];
    float vv[4] = {v.x, v.y, v.z, v.w};
#pragma unroll
    for (int u = 0; u < 4; u++) split2(vv[u], &hi[i + u], &lo[i + u]);
}

__global__ __launch_bounds__(256) void cvt_hi(
    const float* __restrict__ in, bf* __restrict__ hi, int n)
{
    const int i = (blockIdx.x * 256 + threadIdx.x) * 4;
    if (i >= n) return;
    float4 v = *(const float4*)&in[i];
    hi[i + 0] = __float2bfloat16(v.x);
    hi[i + 1] = __float2bfloat16(v.y);
    hi[i + 2] = __float2bfloat16(v.z);
    hi[i + 3] = __float2bfloat16(v.w);
}

// ---------------------------------------------------------------------------
__global__ __launch_bounds__(256) void rmsnorm_cvt(
    const float* __restrict__ in, int ld, int D, const float* __restrict__ w,
    bf* __restrict__ hi, bf* __restrict__ lo)
{
    const int row = blockIdx.x;
    const float* r = in + (size_t)row * ld;
    float ss = 0.0f;
    for (int i = threadIdx.x; i < D; i += 256) { float v = r[i]; ss += v * v; }
#pragma unroll
    for (int o = 32; o > 0; o >>= 1) ss += __shfl_down(ss, o, 64);
    __shared__ float red[4];
    if ((threadIdx.x & 63) == 0) red[threadIdx.x >> 6] = ss;
    __syncthreads();
    ss = red[0] + red[1] + red[2] + red[3];
    const float scale = rsqrtf(ss / (float)D + EPS_RMS);
    for (int i = threadIdx.x; i < D; i += 256) {
        const float v = r[i] * scale * w[i];
        split2(v, &hi[(size_t)row * D + i], &lo[(size_t)row * D + i]);
    }
}

// ---------------------------------------------------------------------------
__global__ __launch_bounds__(256) void rope_k_cvt(
    const float* __restrict__ kvfull, const float* __restrict__ freqs,
    bf* __restrict__ kpeh, bf* __restrict__ kpel)
{
    const int idx = blockIdx.x * 256 + threadIdx.x;   // 65536
    const int i = idx & 31, t = idx >> 5;
    const float f = freqs[t * 32 + i];
    float sn, cs; sincosf(f, &sn, &cs);
    const float x1 = kvfull[(size_t)t * KVFULL_D + KVLORA + 2 * i];
    const float x2 = kvfull[(size_t)t * KVFULL_D + KVLORA + 2 * i + 1];
    split2(x1 * cs - x2 * sn, &kpeh[t * 64 + 2 * i], &kpel[t * 64 + 2 * i]);
    split2(x1 * sn + x2 * cs, &kpeh[t * 64 + 2 * i + 1], &kpel[t * 64 + 2 * i + 1]);
}

// ---------------------------------------------------------------------------
__global__ __launch_bounds__(256) void transpose_v(
    const bf* __restrict__ vh, bf* __restrict__ vT)
{
    __shared__ bf s[32][33];
    const int t0 = blockIdx.x * 32, d0 = blockIdx.y * 32, h = blockIdx.z;
    const int tid = threadIdx.x;
    const int i = tid >> 3, j0 = (tid & 7) * 4;
    const bf* src = vh + ((size_t)(t0 + i) * 16 + h) * 128 + d0 + j0;
#pragma unroll
    for (int u = 0; u < 4; u++) s[i][j0 + u] = src[u];
    __syncthreads();
    const int jj = tid >> 3, i0 = (tid & 7) * 4;
    bf* dst = vT + ((size_t)h * 128 + d0 + jj) * 2048 + t0 + i0;
#pragma unroll
    for (int u = 0; u < 4; u++) dst[u] = s[i0 + u][jj];
}

// ---------------------------------------------------------------------------
// Split-bf16 GEMM (score path), 128x128 tile, 3 MFMAs.
// MODE 1: RoPE on d>=128 + split -> Oh/Ol (q). MODE 2: kn/v split write.
// ---------------------------------------------------------------------------
template <int MODE>
__global__ __launch_bounds__(256) void gemm_split(
    const bf* __restrict__ Ah, const bf* __restrict__ Al,
    const bf* __restrict__ Bh, const bf* __restrict__ Bl,
    const float* __restrict__ freqs,
    float* __restrict__ Cf, bf* __restrict__ Oh, bf* __restrict__ Ol,
    bf* __restrict__ O2, int M, int N, int K)
{
    __shared__ bf sAh[128 * 32], sAl[128 * 32];
    __shared__ bf sBh[128 * 32], sBl[128 * 32];

    const int tid = threadIdx.x;
    const int lane = tid & 63, wave = tid >> 6;
    const int row0 = blockIdx.y * 128, col0 = blockIdx.x * 128;
    const int wm = (wave & 1) * 64, wn = (wave >> 1) * 64;
    const int fr = lane & 15, quad = lane >> 4;

    f32x4 acc[4][4];
#pragma unroll
    for (int i = 0; i < 4; i++)
#pragma unroll
        for (int j = 0; j < 4; j++) acc[i][j] = (f32x4){0.f, 0.f, 0.f, 0.f};

    const int trow = tid >> 2;
    const int tcol = (tid & 3) * 8;
    const size_t ldsoff = (size_t)wave * 1024;

    for (int kt = 0; kt < K; kt += 32) {
        __syncthreads();
        GLOAD_LDS16(Ah + (size_t)(row0 + trow) * K + kt + tcol,      (char*)sAh + ldsoff);
        GLOAD_LDS16(Ah + (size_t)(row0 + 64 + trow) * K + kt + tcol, (char*)sAh + 4096 + ldsoff);
        GLOAD_LDS16(Al + (size_t)(row0 + trow) * K + kt + tcol,      (char*)sAl + ldsoff);
        GLOAD_LDS16(Al + (size_t)(row0 + 64 + trow) * K + kt + tcol, (char*)sAl + 4096 + ldsoff);
        GLOAD_LDS16(Bh + (size_t)(col0 + trow) * K + kt + tcol,      (char*)sBh + ldsoff);
        GLOAD_LDS16(Bh + (size_t)(col0 + 64 + trow) * K + kt + tcol, (char*)sBh + 4096 + ldsoff);
        GLOAD_LDS16(Bl + (size_t)(col0 + trow) * K + kt + tcol,      (char*)sBl + ldsoff);
        GLOAD_LDS16(Bl + (size_t)(col0 + 64 + trow) * K + kt + tcol, (char*)sBl + 4096 + ldsoff);
        __syncthreads();

        bf16x8 a_h[4], a_l[4], b_h[4], b_l[4];
#pragma unroll
        for (int mt = 0; mt < 4; mt++) {
            const int r = (wm + mt * 16 + fr) * 32 + quad * 8;
            a_h[mt] = *(const bf16x8*)&sAh[r];
            a_l[mt] = *(const bf16x8*)&sAl[r];
        }
#pragma unroll
        for (int nt = 0; nt < 4; nt++) {
            const int r = (wn + nt * 16 + fr) * 32 + quad * 8;
            b_h[nt] = *(const bf16x8*)&sBh[r];
            b_l[nt] = *(const bf16x8*)&sBl[r];
        }
#pragma unroll
        for (int mt = 0; mt < 4; mt++)
#pragma unroll
            for (int nt = 0; nt < 4; nt++) {
                acc[mt][nt] = __builtin_amdgcn_mfma_f32_16x16x32_bf16(
                    a_l[mt], b_h[nt], acc[mt][nt], 0, 0, 0);
                acc[mt][nt] = __builtin_amdgcn_mfma_f32_16x16x32_bf16(
                    a_h[mt], b_l[nt], acc[mt][nt], 0, 0, 0);
                acc[mt][nt] = __builtin_amdgcn_mfma_f32_16x16x32_bf16(
                    a_h[mt], b_h[nt], acc[mt][nt], 0, 0, 0);
            }
    }

#pragma unroll
    for (int mt = 0; mt < 4; mt++)
#pragma unroll
        for (int nt = 0; nt < 4; nt++) {
            const int colb = col0 + wn + nt * 16;
            const int col = colb + fr;
            if (MODE == 1) {
                const int d0 = colb % 192;
                const bool rope = (d0 >= 128);
                const int ii = (d0 + fr - 128) >> 1;
#pragma unroll
                for (int r = 0; r < 4; r++) {
                    const int row = row0 + wm + mt * 16 + quad * 4 + r;
                    float v = acc[mt][nt][r];
                    if (rope) {
                        const float other = __shfl_xor(v, 1);
                        float sn, cs; sincosf(freqs[row * 32 + ii], &sn, &cs);
                        v = (fr & 1) ? (other * sn + v * cs) : (v * cs - other * sn);
                    }
                    bf h8, l8; split2(v, &h8, &l8);
                    Oh[(size_t)row * N + col] = h8;
                    Ol[(size_t)row * N + col] = l8;
                }
            } else {
                const int hh = col >> 8;
                const int d = col & 255;
#pragma unroll
                for (int r = 0; r < 4; r++) {
                    const int row = row0 + wm + mt * 16 + quad * 4 + r;
                    const float v = acc[mt][nt][r];
                    if (d < 128) {
                        bf h8, l8; split2(v, &h8, &l8);
                        Oh[(size_t)row * 2048 + hh * 128 + d] = h8;
                        Ol[(size_t)row * 2048 + hh * 128 + d] = l8;
                    } else {
                        O2[(size_t)row * 2048 + hh * 128 + (d - 128)] = __float2bfloat16(v);
                    }
                }
            }
        }
}

// ---------------------------------------------------------------------------
// Split-bf16 GEMM, 64x64 tile (small-N shapes: qa N=768, kvfull N=576).
// ---------------------------------------------------------------------------
__global__ __launch_bounds__(256) void gemm_split64(
    const bf* __restrict__ Ah, const bf* __restrict__ Al,
    const bf* __restrict__ Bh, const bf* __restrict__ Bl,
    float* __restrict__ Cf, int M, int N, int K)
{
    __shared__ bf sAh[64 * 32], sAl[64 * 32];
    __shared__ bf sBh[64 * 32], sBl[64 * 32];

    const int tid = threadIdx.x;
    const int lane = tid & 63, wave = tid >> 6;
    const int row0 = blockIdx.y * 64, col0 = blockIdx.x * 64;
    const int wm = (wave & 1) * 32, wn = (wave >> 1) * 32;
    const int fr = lane & 15, quad = lane >> 4;

    f32x4 acc[2][2];
#pragma unroll
    for (int i = 0; i < 2; i++)
#pragma unroll
        for (int j = 0; j < 2; j++) acc[i][j] = (f32x4){0.f, 0.f, 0.f, 0.f};

    const int trow = tid >> 2;
    const int tcol = (tid & 3) * 8;
    const size_t ldsoff = (size_t)wave * 1024;

    for (int kt = 0; kt < K; kt += 32) {
        __syncthreads();
        GLOAD_LDS16(Ah + (size_t)(row0 + trow) * K + kt + tcol, (char*)sAh + ldsoff);
        GLOAD_LDS16(Al + (size_t)(row0 + trow) * K + kt + tcol, (char*)sAl + ldsoff);
        GLOAD_LDS16(Bh + (size_t)(col0 + trow) * K + kt + tcol, (char*)sBh + ldsoff);
        GLOAD_LDS16(Bl + (size_t)(col0 + trow) * K + kt + tcol, (char*)sBl + ldsoff);
        __syncthreads();

        bf16x8 a_h[2], a_l[2], b_h[2], b_l[2];
#pragma unroll
        for (int mt = 0; mt < 2; mt++) {
            const int r = (wm + mt * 16 + fr) * 32 + quad * 8;
            a_h[mt] = *(const bf16x8*)&sAh[r];
            a_l[mt] = *(const bf16x8*)&sAl[r];
        }
#pragma unroll
        for (int nt = 0; nt < 2; nt++) {
            const int r = (wn + nt * 16 + fr) * 32 + quad * 8;
            b_h[nt] = *(const bf16x8*)&sBh[r];
            b_l[nt] = *(const bf16x8*)&sBl[r];
        }
#pragma unroll
        for (int mt = 0; mt < 2; mt++)
#pragma unroll
            for (int nt = 0; nt < 2; nt++) {
                acc[mt][nt] = __builtin_amdgcn_mfma_f32_16x16x32_bf16(
                    a_l[mt], b_h[nt], acc[mt][nt], 0, 0, 0);
                acc[mt][nt] = __builtin_amdgcn_mfma_f32_16x16x32_bf16(
                    a_h[mt], b_l[nt], acc[mt][nt], 0, 0, 0);
                acc[mt][nt] = __builtin_amdgcn_mfma_f32_16x16x32_bf16(
                    a_h[mt], b_h[nt], acc[mt][nt], 0, 0, 0);
            }
    }

#pragma unroll
    for (int mt = 0; mt < 2; mt++)
#pragma unroll
        for (int nt = 0; nt < 2; nt++)
#pragma unroll
            for (int r = 0; r < 4; r++)
                Cf[(size_t)(row0 + wm + mt * 16 + quad * 4 + r) * N +
                   col0 + wn + nt * 16 + fr] = acc[mt][nt][r];
}

// ---------------------------------------------------------------------------
// Plain bf16 GEMM (post-softmax out-projection): C = A @ B^T, single MFMA.
// ---------------------------------------------------------------------------
__global__ __launch_bounds__(256) void gemm_bf16(
    const bf* __restrict__ Ah, const bf* __restrict__ Bh,
    float* __restrict__ Cf, int M, int N, int K)
{
    __shared__ bf sAh[128 * 32];
    __shared__ bf sBh[128 * 32];

    const int tid = threadIdx.x;
    const int lane = tid & 63, wave = tid >> 6;
    const int row0 = blockIdx.y * 128, col0 = blockIdx.x * 128;
    const int wm = (wave & 1) * 64, wn = (wave >> 1) * 64;
    const int fr = lane & 15, quad = lane >> 4;

    f32x4 acc[4][4];
#pragma unroll
    for (int i = 0; i < 4; i++)
#pragma unroll
        for (int j = 0; j < 4; j++) acc[i][j] = (f32x4){0.f, 0.f, 0.f, 0.f};

    const int trow = tid >> 2;
    const int tcol = (tid & 3) * 8;
    const size_t ldsoff = (size_t)wave * 1024;

    for (int kt = 0; kt < K; kt += 32) {
        __syncthreads();
        GLOAD_LDS16(Ah + (size_t)(row0 + trow) * K + kt + tcol,      (char*)sAh + ldsoff);
        GLOAD_LDS16(Ah + (size_t)(row0 + 64 + trow) * K + kt + tcol, (char*)sAh + 4096 + ldsoff);
        GLOAD_LDS16(Bh + (size_t)(col0 + trow) * K + kt + tcol,      (char*)sBh + ldsoff);
        GLOAD_LDS16(Bh + (size_t)(col0 + 64 + trow) * K + kt + tcol, (char*)sBh + 4096 + ldsoff);
        __syncthreads();

        bf16x8 a_h[4], b_h[4];
#pragma unroll
        for (int mt = 0; mt < 4; mt++)
            a_h[mt] = *(const bf16x8*)&sAh[(wm + mt * 16 + fr) * 32 + quad * 8];
#pragma unroll
        for (int nt = 0; nt < 4; nt++)
            b_h[nt] = *(const bf16x8*)&sBh[(wn + nt * 16 + fr) * 32 + quad * 8];
#pragma unroll
        for (int mt = 0; mt < 4; mt++)
#pragma unroll
            for (int nt = 0; nt < 4; nt++)
                acc[mt][nt] = __builtin_amdgcn_mfma_f32_16x16x32_bf16(
                    a_h[mt], b_h[nt], acc[mt][nt], 0, 0, 0);
    }

#pragma unroll
    for (int mt = 0; mt < 4; mt++)
#pragma unroll
        for (int nt = 0; nt < 4; nt++)
#pragma unroll
            for (int r = 0; r < 4; r++)
                Cf[(size_t)(row0 + wm + mt * 16 + quad * 4 + r) * N +
                   col0 + wn + nt * 16 + fr] = acc[mt][nt][r];
}

// ---------------------------------------------------------------------------
// Register-direct monolithic MFMA flash attention. 512 blocks = (h, qt),
// heavy/light paired, sequential k (L2 convoy preserved).
// Q/K/V fragments: global->VGPR dwordx4 (each frag consumed by one wave only;
// compiler pipelines loads with its own counted vmcnt -> no barriers in QK).
// LDS only for Ps (cross-wave P for PV) + redM/redS: 2 lgkm-only barriers
// per k-tile. LDS 19.5 KB.
// ---------------------------------------------------------------------------
__global__ __launch_bounds__(256, 2) void attn_mfma(
    const bf* __restrict__ qh, const bf* __restrict__ ql,
    const bf* __restrict__ knh, const bf* __restrict__ knl,
    const bf* __restrict__ kpeh, const bf* __restrict__ kpel,
    const bf* __restrict__ vT, bf* __restrict__ yh)
{
    const int bid = blockIdx.x;
    const int h = bid & 15;
    const int qt = (bid < 256) ? (31 - (bid >> 4)) : ((bid - 256) >> 4);

    const int tid = threadIdx.x;
    const int lane = tid & 63, wave = tid >> 6;
    const int fr = lane & 15, quad = lane >> 4;
    const int wn = wave * 32;

    __shared__ __align__(16) bf Ps[64 * 136];      // stride 136: 2-way banks
    __shared__ __align__(16) float redM[64 * 4];
    __shared__ __align__(16) float redS[64 * 4];

    float m_i[16], l_i[16], al[16];
    f32x4 O[4][2];
#pragma unroll
    for (int i = 0; i < 16; i++) { m_i[i] = -INFINITY; l_i[i] = 0.0f; }
#pragma unroll
    for (int mt = 0; mt < 4; mt++)
#pragma unroll
        for (int nt = 0; nt < 2; nt++) O[mt][nt] = (f32x4){0.f, 0.f, 0.f, 0.f};

    const int q0 = qt * 64;
    const int nkt = ((qt + 1) * 64 + 127) >> 7;

    // Q fragment base offsets (constant across k-tiles)
    size_t qoff[4];
#pragma unroll
    for (int mt = 0; mt < 4; mt++)
        qoff[mt] = ((size_t)(q0 + mt * 16 + fr) * 16 + h) * 192 + quad * 8;
    // V fragment base offsets (per nt)
    size_t voff[2];
#pragma unroll
    for (int nt = 0; nt < 2; nt++)
        voff[nt] = ((size_t)(h * 128 + wn + nt * 16 + fr)) * 2048 + quad * 8;

    for (int kt = 0; kt < nkt; kt++) {
        const int k0 = kt * 128;
        f32x4 S[4][2];
#pragma unroll
        for (int mt = 0; mt < 4; mt++)
#pragma unroll
            for (int nt = 0; nt < 2; nt++) S[mt][nt] = (f32x4){0.f, 0.f, 0.f, 0.f};

        // ---- S = Q.K^T over 192 dims: register-direct, no barriers ----
#pragma unroll
        for (int ch = 0; ch < 6; ch++) {
            const int d0 = ch * 32;
            bf16x8 a_h[4], a_l[4], b_h[2], b_l[2];
#pragma unroll
            for (int mt = 0; mt < 4; mt++) {
                a_h[mt] = *(const bf16x8*)&qh[qoff[mt] + d0];
                a_l[mt] = *(const bf16x8*)&ql[qoff[mt] + d0];
            }
            if (d0 < 128) {
#pragma unroll
                for (int nt = 0; nt < 2; nt++) {
                    const size_t koff =
                        ((size_t)(k0 + wn + nt * 16 + fr) * 16 + h) * 128 + d0 + quad * 8;
                    b_h[nt] = *(const bf16x8*)&knh[koff];
                    b_l[nt] = *(const bf16x8*)&knl[koff];
                }
            } else {
#pragma unroll
                for (int nt = 0; nt < 2; nt++) {
                    const size_t koff =
                        (size_t)(k0 + wn + nt * 16 + fr) * 64 + (d0 - 128) + quad * 8;
                    b_h[nt] = *(const bf16x8*)&kpeh[koff];
                    b_l[nt] = *(const bf16x8*)&kpel[koff];
                }
            }
#pragma unroll
            for (int mt = 0; mt < 4; mt++)
#pragma unroll
                for (int nt = 0; nt < 2; nt++) {
                    S[mt][nt] = __builtin_amdgcn_mfma_f32_16x16x32_bf16(
                        a_l[mt], b_h[nt], S[mt][nt], 0, 0, 0);
                    S[mt][nt] = __builtin_amdgcn_mfma_f32_16x16x32_bf16(
                        a_h[mt], b_l[nt], S[mt][nt], 0, 0, 0);
                    S[mt][nt] = __builtin_amdgcn_mfma_f32_16x16x32_bf16(
                        a_h[mt], b_h[nt], S[mt][nt], 0, 0, 0);
                }
        }

        // ---- softmax part 1: scale, causal mask, row-max ----
#pragma unroll
        for (int mt = 0; mt < 4; mt++)
#pragma unroll
            for (int rr = 0; rr < 4; rr++) {
                const int ri = mt * 16 + quad * 4 + rr;
                const int rowg = q0 + ri;
                float v0 = S[mt][0][rr] * SOFTSCALE;
                float v1 = S[mt][1][rr] * SOFTSCALE;
                if (k0 + wn + fr > rowg)      v0 = -INFINITY;
                if (k0 + wn + 16 + fr > rowg) v1 = -INFINITY;
                S[mt][0][rr] = v0; S[mt][1][rr] = v1;
                float pm = fmaxf(v0, v1);
#pragma unroll
                for (int o = 1; o < 16; o <<= 1) pm = fmaxf(pm, __shfl_xor(pm, o, 64));
                if (fr == 0) redM[ri * 4 + wave] = pm;
            }

        // issue V loads now: latency hides under exp phase (reg-direct)
        bf16x8 bv[4][2];
#pragma unroll
        for (int vc = 0; vc < 4; vc++)
#pragma unroll
            for (int nt = 0; nt < 2; nt++)
                bv[vc][nt] = *(const bf16x8*)&vT[voff[nt] + k0 + vc * 32];

        WAITL();
        BARRIER();   // B1: redM visible (lgkm only; global loads stay in flight)

        // ---- softmax part 2: exp, row-sum, Ps write ----
#pragma unroll
        for (int mt = 0; mt < 4; mt++)
#pragma unroll
            for (int rr = 0; rr < 4; rr++) {
                const int idx = mt * 4 + rr;
                const int ri = mt * 16 + quad * 4 + rr;
                const float4 g = *(const float4*)&redM[ri * 4];
                const float gm = fmaxf(fmaxf(g.x, g.y), fmaxf(g.z, g.w));
                const float mn = fmaxf(m_i[idx], gm);
                al[idx] = __expf(m_i[idx] - mn);
                m_i[idx] = mn;
                const float p0 = __expf(S[mt][0][rr] - mn);
                const float p1 = __expf(S[mt][1][rr] - mn);
                Ps[ri * 136 + wn + fr]      = __float2bfloat16(p0);
                Ps[ri * 136 + wn + 16 + fr] = __float2bfloat16(p1);
                float ps = p0 + p1;
#pragma unroll
                for (int o = 1; o < 16; o <<= 1) ps += __shfl_xor(ps, o, 64);
                if (fr == 0) redS[ri * 4 + wave] = ps;
            }
#pragma unroll
        for (int mt = 0; mt < 4; mt++)
#pragma unroll
            for (int nt = 0; nt < 2; nt++)
#pragma unroll
                for (int rr = 0; rr < 4; rr++) O[mt][nt][rr] *= al[mt * 4 + rr];

        WAITL();
        BARRIER();   // B2: redS + Ps visible

#pragma unroll
        for (int mt = 0; mt < 4; mt++)
#pragma unroll
            for (int rr = 0; rr < 4; rr++) {
                const int idx = mt * 4 + rr;
                const int ri = mt * 16 + quad * 4 + rr;
                const float4 s4 = *(const float4*)&redS[ri * 4];
                l_i[idx] = l_i[idx] * al[idx] + (s4.x + s4.y + s4.z + s4.w);
            }

        // ---- PV: O += P @ V over 128 keys (4 chunks of 32) ----
#pragma unroll
        for (int vc = 0; vc < 4; vc++) {
            bf16x8 ap[4];
#pragma unroll
            for (int mt = 0; mt < 4; mt++)
                ap[mt] = *(const bf16x8*)&Ps[(mt * 16 + fr) * 136 + vc * 32 + quad * 8];
#pragma unroll
            for (int mt = 0; mt < 4; mt++)
#pragma unroll
                for (int nt = 0; nt < 2; nt++)
                    O[mt][nt] = __builtin_amdgcn_mfma_f32_16x16x32_bf16(
                        ap[mt], bv[vc][nt], O[mt][nt], 0, 0, 0);
        }
        // next tile's Ps/redM writes are W-A-R-safe: all waves' PV ds_reads
        // retire before their consuming MFMAs, which precede next B1.
    }

    // ---- epilogue: y = O / l (bf16) ----
#pragma unroll
    for (int mt = 0; mt < 4; mt++)
#pragma unroll
        for (int rr = 0; rr < 4; rr++) {
            const float inv = 1.0f / l_i[mt * 4 + rr];
            const int row = q0 + mt * 16 + quad * 4 + rr;
#pragma unroll
            for (int nt = 0; nt < 2; nt++)
                yh[((size_t)row * 16 + h) * 128 + wn + nt * 16 + fr] =
                    __float2bfloat16(O[mt][nt][rr] * inv);
        }
}

// ---------------------------------------------------------------------------
// Workspace (peak < 85 MB):
//  A  @0        : xh(8.39) xl(8.39) -> yh@0, vT@8.39
//  AR @16.78    : (16.78) GEMM temporaries -> woh
//  persistent   : qh@33.55 ql@46.14 knh@58.72 knl@67.11 vh@75.50
//                 kpeh@83.89 kpel@84.15
// ---------------------------------------------------------------------------
extern "C" void kernel_launch(void* const* d_in, const int* in_sizes, int n_in,
                              void* d_out, int out_size, void* d_ws, size_t ws_size,
                              hipStream_t stream)
{
    const float* x        = (const float*)d_in[0];
    const float* freqs    = (const float*)d_in[1];
    const float* wq_a     = (const float*)d_in[3];
    const float* q_norm_w = (const float*)d_in[4];
    const float* wq_b     = (const float*)d_in[5];
    const float* wkv_a    = (const float*)d_in[6];
    const float* kv_norm_w= (const float*)d_in[7];
    const float* wkv_b    = (const float*)d_in[8];
    const float* wo       = (const float*)d_in[9];
    float* out            = (float*)d_out;

    char* ws = (char*)d_ws;
    bf* xh = (bf*)(ws);
    bf* xl = (bf*)(ws + 8388608);
    bf* yh = (bf*)(ws);                   // after x dead
    bf* vT = (bf*)(ws + 8388608);         // after x dead
    char* AR = ws + 16777216;
    bf*    wah    = (bf*)(AR);
    bf*    wal    = (bf*)(AR + 3145728);
    float* qa     = (float*)(AR + 6291456);
    bf*    qah    = (bf*)(AR);
    bf*    qal    = (bf*)(AR + 3145728);
    bf*    wbh    = (bf*)(AR + 6291456);
    bf*    wbl    = (bf*)(AR + 11010048);
    bf*    kah    = (bf*)(AR);
    bf*    kal    = (bf*)(AR + 2359296);
    float* kvfull = (float*)(AR + 4718592);
    bf*    ckvh   = (bf*)(AR + 9437184);
    bf*    ckvl   = (bf*)(AR + 11534336);
    bf*    wvh    = (bf*)(AR);
    bf*    wvl    = (bf*)(AR + 4194304);
    bf*    woh    = (bf*)(AR);
    bf* qh   = (bf*)(ws + 33554432);
    bf* ql   = (bf*)(ws + 46137344);
    bf* knh  = (bf*)(ws + 58720256);
    bf* knl  = (bf*)(ws + 67108864);
    bf* vh   = (bf*)(ws + 75497472);
    bf* kpeh = (bf*)(ws + 83886080);
    bf* kpel = (bf*)(ws + 84148224);

    dim3 blk(256);

    cvt_split<<<4096, blk, 0, stream>>>(x, xh, xl, D_MODEL * D_MODEL);
    cvt_split<<<1536, blk, 0, stream>>>(wq_a, wah, wal, QLORA * D_MODEL);
    gemm_split64<<<dim3(12, 32), blk, 0, stream>>>(
        xh, xl, wah, wal, qa, T_DIM, QLORA, D_MODEL);
    rmsnorm_cvt<<<T_DIM, blk, 0, stream>>>(qa, QLORA, QLORA, q_norm_w, qah, qal);
    cvt_split<<<2304, blk, 0, stream>>>(wq_b, wbh, wbl, 3072 * QLORA);
    gemm_split<1><<<dim3(24, 16), blk, 0, stream>>>(
        qah, qal, wbh, wbl, freqs, nullptr, qh, ql, nullptr,
        T_DIM, 3072, QLORA);
    cvt_split<<<1152, blk, 0, stream>>>(wkv_a, kah, kal, KVFULL_D * D_MODEL);
    gemm_split64<<<dim3(9, 32), blk, 0, stream>>>(
        xh, xl, kah, kal, kvfull, T_DIM, KVFULL_D, D_MODEL);
    rope_k_cvt<<<256, blk, 0, stream>>>(kvfull, freqs, kpeh, kpel);
    rmsnorm_cvt<<<T_DIM, blk, 0, stream>>>(kvfull, KVFULL_D, KVLORA, kv_norm_w, ckvh, ckvl);
    cvt_split<<<2048, blk, 0, stream>>>(wkv_b, wvh, wvl, 4096 * KVLORA);
    gemm_split<2><<<dim3(32, 16), blk, 0, stream>>>(
        ckvh, ckvl, wvh, wvl, nullptr, nullptr, knh, knl, vh,
        T_DIM, 4096, KVLORA);
    transpose_v<<<dim3(64, 4, 16), blk, 0, stream>>>(vh, vT);
    attn_mfma<<<dim3(512), blk, 0, stream>>>(
        qh, ql, knh, knl, kpeh, kpel, vT, yh);
    cvt_hi<<<4096, blk, 0, stream>>>(wo, woh, D_MODEL * D_MODEL);
    gemm_bf16<<<dim3(16, 16), blk, 0, stream>>>(
        yh, woh, out, T_DIM, D_MODEL, D_MODEL);
}